// Round 6
// baseline (78.505 us; speedup 1.0000x reference)
//
#include <hip/hip_runtime.h>
#include <hip/hip_bf16.h>

#define N 1024
#define BATCH 256

typedef __attribute__((ext_vector_type(4))) short short4v;
typedef __attribute__((ext_vector_type(8))) short short8;
typedef __attribute__((ext_vector_type(4))) float f32x4;

static __device__ __forceinline__ ushort bfbits(float f) {
    union { __hip_bfloat16 h; ushort u; } cv; cv.h = __float2bfloat16(f); return cv.u;
}
static __device__ __forceinline__ float bf2f(ushort u) {
    union { ushort u; __hip_bfloat16 h; } cv; cv.u = u; return __bfloat162float(cv.h);
}

// ---------------------------------------------------------------------------
// K1: Ph/Pl = bf16 hi/lo split of exp(W); psum[slab][j] = 16-row column sums.
// grid 256 = 64 row-slabs(16) x 4 col-groups(256).  f32x4 loads (16B/lane).
// ---------------------------------------------------------------------------
__global__ __launch_bounds__(256) void k1_psplit(const float* __restrict__ W,
                                                 float* __restrict__ psum,
                                                 ushort* __restrict__ Ph,
                                                 ushort* __restrict__ Pl) {
    const int t = threadIdx.x, lane = t & 63, w = t >> 6;
    const int cg = blockIdx.x & 3, slab = blockIdx.x >> 2;
    const int c = cg * 256 + lane * 4;
    __shared__ f32x4 sm[4][64];
    f32x4 acc = {0.f, 0.f, 0.f, 0.f};
#pragma unroll
    for (int it = 0; it < 4; ++it) {
        const int row = slab * 16 + w * 4 + it;
        const f32x4 v = *(const f32x4*)(W + row * N + c);
        short4v ph, pl;
        f32x4 e;
#pragma unroll
        for (int x = 0; x < 4; ++x) {
            e[x] = __expf(v[x]);
            const ushort h = bfbits(e[x]);
            ph[x] = (short)h;
            pl[x] = (short)bfbits(e[x] - bf2f(h));
        }
        *(short4v*)(Ph + row * N + c) = ph;
        *(short4v*)(Pl + row * N + c) = pl;
        acc += e;
    }
    sm[w][lane] = acc;
    __syncthreads();
    if (t < 64)
        *(f32x4*)(psum + slab * N + c) =
            sm[0][lane] + sm[1][lane] + sm[2][lane] + sm[3][lane];
}

// ---------------------------------------------------------------------------
// K2: lcs = log(colsum) from 64 slab partials; Qh/Ql = split of exp(la-lcs).
// grid 256 = 16 m-groups(16 rows) x 16 col-groups(64 cols) — full CU coverage.
// ---------------------------------------------------------------------------
__global__ __launch_bounds__(256) void k2_qsplit(const float* __restrict__ la,
                                                 const float* __restrict__ psum,
                                                 ushort* __restrict__ Qh,
                                                 ushort* __restrict__ Ql) {
    const int t = threadIdx.x;
    const int cg = blockIdx.x & 15, mg = blockIdx.x >> 4;
    const int c0 = cg * 64;
    __shared__ float smred[4][64];
    __shared__ float lcs[64];

    // colsum for 64 cols over 64 slabs: col = t&63, slab-group = t>>6 (16 each)
    {
        const int col = t & 63, sg = t >> 6;
        float a = 0.f;
#pragma unroll
        for (int i = 0; i < 16; ++i)
            a += psum[(sg * 16 + i) * N + c0 + col];
        smred[sg][col] = a;
    }
    __syncthreads();
    if (t < 64)
        lcs[t] = __logf(smred[0][t] + smred[1][t] + smred[2][t] + smred[3][t]);
    __syncthreads();

    // Q split: 16 rows x 64 cols, 4 elems/thread
    const int row = mg * 16 + (t >> 4);
    const int cc  = (t & 15) * 4;
    const f32x4 v = *(const f32x4*)(la + row * N + c0 + cc);
    short4v qh, ql;
#pragma unroll
    for (int x = 0; x < 4; ++x) {
        const float qv = __expf(v[x] - lcs[cc + x]);
        const ushort h = bfbits(qv);
        qh[x] = (short)h;
        ql[x] = (short)bfbits(qv - bf2f(h));
    }
    *(short4v*)(Qh + row * N + c0 + cc) = qh;
    *(short4v*)(Ql + row * N + c0 + cc) = ql;
}

// ---------------------------------------------------------------------------
// K3: out[m][i] = log( sum_j Q[m][j]*P[i][j] ), split-3 bf16 MFMA, NO LDS
// staging.  Round-4 was LDS-read-bound (12 ds_read_b128 per 6 MFMAs ->
// ~1150cy LDS pipe vs ~290cy MFMA per iter per CU).  The 16x16x32 fragment
// (lane=row l&15, 8 contiguous k at (l>>4)*8) loads 64B-line-perfect straight
// from K-major global: lanes {l,l+16,l+32,l+48} cover one row's 64B.
// 256 blocks (8 m x 32 i), 512 thr = 8 waves: 2x2 quadrants x K-split-2
// (each wave K=512 = 16 chunks of 32).  Depth-8 register prefetch pipeline;
// two alternating accumulators; one barrier; 8KB LDS K-reduce; log+store.
// Default XCD round-robin (b%8) keeps P i-tiles XCD-L2-resident.
// ---------------------------------------------------------------------------
__global__ __launch_bounds__(512) void k3_mm(const ushort* __restrict__ Qh,
                                             const ushort* __restrict__ Ql,
                                             const ushort* __restrict__ Ph,
                                             const ushort* __restrict__ Pl,
                                             float* __restrict__ out) {
    __shared__ f32x4 red[512];

    const int t    = threadIdx.x;
    const int lane = t & 63;
    const int wid  = t >> 6;              // 0..7
    const int wm   = (wid >> 1) & 1;
    const int wn   = wid & 1;
    const int g    = wid >> 2;            // K-half
    const int m0   = (blockIdx.x >> 5) * 32;
    const int i0   = (blockIdx.x & 31) * 32;

    const int kb = g * 512 + (lane >> 4) * 8;   // lane k-base within half
    const ushort* pAh = Qh + (m0 + wm * 16 + (lane & 15)) * N + kb;
    const ushort* pAl = Ql + (m0 + wm * 16 + (lane & 15)) * N + kb;
    const ushort* pBh = Ph + (i0 + wn * 16 + (lane & 15)) * N + kb;
    const ushort* pBl = Pl + (i0 + wn * 16 + (lane & 15)) * N + kb;

    // depth-8 register prefetch: 32 loads in flight, then steady-state
    short8 rAh[8], rAl[8], rBh[8], rBl[8];
#pragma unroll
    for (int c = 0; c < 8; ++c) {
        rAh[c] = *(const short8*)(pAh + c * 32);
        rAl[c] = *(const short8*)(pAl + c * 32);
        rBh[c] = *(const short8*)(pBh + c * 32);
        rBl[c] = *(const short8*)(pBl + c * 32);
    }

    f32x4 acc0 = {0.f, 0.f, 0.f, 0.f};
    f32x4 acc1 = {0.f, 0.f, 0.f, 0.f};

#pragma unroll
    for (int ks = 0; ks < 16; ++ks) {
        const int c = ks & 7;
        const short8 ah = rAh[c], al = rAl[c], bh = rBh[c], bl = rBl[c];
        if (ks < 8) {   // prefetch chunk ks+8 (static idx after unroll)
            rAh[c] = *(const short8*)(pAh + (ks + 8) * 32);
            rAl[c] = *(const short8*)(pAl + (ks + 8) * 32);
            rBh[c] = *(const short8*)(pBh + (ks + 8) * 32);
            rBl[c] = *(const short8*)(pBl + (ks + 8) * 32);
        }
        if (ks & 1) {
            acc1 = __builtin_amdgcn_mfma_f32_16x16x32_bf16(ah, bh, acc1, 0, 0, 0);
            acc1 = __builtin_amdgcn_mfma_f32_16x16x32_bf16(ah, bl, acc1, 0, 0, 0);
            acc1 = __builtin_amdgcn_mfma_f32_16x16x32_bf16(al, bh, acc1, 0, 0, 0);
        } else {
            acc0 = __builtin_amdgcn_mfma_f32_16x16x32_bf16(ah, bh, acc0, 0, 0, 0);
            acc0 = __builtin_amdgcn_mfma_f32_16x16x32_bf16(ah, bl, acc0, 0, 0, 0);
            acc0 = __builtin_amdgcn_mfma_f32_16x16x32_bf16(al, bh, acc0, 0, 0, 0);
        }
    }

    red[wid * 64 + lane] = acc0 + acc1;
    __syncthreads();
    if (wid < 4) {   // partner wave wid+4 holds the other K-half
        const f32x4 s = red[wid * 64 + lane] + red[(wid + 4) * 64 + lane];
        const int om = m0 + wm * 16 + (lane >> 4) * 4;
        const int oi = i0 + wn * 16 + (lane & 15);
#pragma unroll
        for (int r = 0; r < 4; ++r)
            out[(om + r) * N + oi] = __logf(s[r]);
    }
}

// ---------------------------------------------------------------------------
extern "C" void kernel_launch(void* const* d_in, const int* in_sizes, int n_in,
                              void* d_out, int out_size, void* d_ws, size_t ws_size,
                              hipStream_t stream) {
    const float* la = (const float*)d_in[0];   // [256][1024]
    const float* W  = (const float*)d_in[1];   // [1024][1024]
    float* out = (float*)d_out;                // [256][1024]

    char* ws = (char*)d_ws;
    float*  psum = (float*)ws;                             // 256 KB (64 slabs)
    ushort* Ph   = (ushort*)(ws + (256 << 10));            // 2 MB
    ushort* Pl   = Ph + (size_t)N * N;                     // 2 MB
    ushort* Qh   = Pl + (size_t)N * N;                     // 512 KB
    ushort* Ql   = Qh + (size_t)BATCH * N;                 // 512 KB

    k1_psplit<<<256, 256, 0, stream>>>(W, psum, Ph, Pl);
    k2_qsplit<<<256, 256, 0, stream>>>(la, psum, Qh, Ql);
    k3_mm<<<256, 512, 0, stream>>>(Qh, Ql, Ph, Pl, out);
}